// Round 4
// baseline (87.514 us; speedup 1.0000x reference)
//
#include <hip/hip_runtime.h>
#include <hip/hip_bf16.h>

// ---- problem constants: B=128, D=1024, ADA=1024, R=8, 4*D*R=32768 ----

typedef __attribute__((ext_vector_type(8))) __bf16 bf16x8;
typedef __attribute__((ext_vector_type(8))) short short8v;
typedef __attribute__((ext_vector_type(4))) float f32x4;

__device__ __forceinline__ float gelu_exact(float v) {
    return 0.5f * v * (1.0f + erff(v * 0.7071067811865476f));
}
__device__ __forceinline__ unsigned short f2bf(float f) {
    union { float f; unsigned u; } c; c.f = f;
    return (unsigned short)((c.u + 0x7FFFu + ((c.u >> 16) & 1u)) >> 16);
}

// ---------- LayerNorm(ada_emb) -> c_bf16 ; cast x -> x_bf16 ----------
__global__ __launch_bounds__(256) void ln_cast_kernel(
    const float* __restrict__ ada, const float* __restrict__ g, const float* __restrict__ be,
    const float* __restrict__ x, unsigned short* __restrict__ cbf, unsigned short* __restrict__ xbf)
{
    int b = blockIdx.x, t = threadIdx.x;
    float4 v = ((const float4*)(ada + b * 1024))[t];
    float s  = v.x + v.y + v.z + v.w;
    float ss = v.x*v.x + v.y*v.y + v.z*v.z + v.w*v.w;
    #pragma unroll
    for (int off = 32; off; off >>= 1) { s += __shfl_xor(s, off); ss += __shfl_xor(ss, off); }
    __shared__ float rs[4], rss[4];
    int wid = t >> 6;
    if ((t & 63) == 0) { rs[wid] = s; rss[wid] = ss; }
    __syncthreads();
    float S  = rs[0] + rs[1] + rs[2] + rs[3];
    float SS = rss[0] + rss[1] + rss[2] + rss[3];
    float mu = S * (1.0f / 1024.0f);
    float rstd = rsqrtf(SS * (1.0f / 1024.0f) - mu * mu + 1e-5f);
    float4 gv = ((const float4*)g)[t];
    float4 bv = ((const float4*)be)[t];
    ushort4 o;
    o.x = f2bf((v.x - mu) * rstd * gv.x + bv.x);
    o.y = f2bf((v.y - mu) * rstd * gv.y + bv.y);
    o.z = f2bf((v.z - mu) * rstd * gv.z + bv.z);
    o.w = f2bf((v.w - mu) * rstd * gv.w + bv.w);
    ((ushort4*)(cbf + b * 1024))[t] = o;
    float4 xv = ((const float4*)(x + b * 1024))[t];
    ushort4 xo;
    xo.x = f2bf(xv.x); xo.y = f2bf(xv.y); xo.z = f2bf(xv.z); xo.w = f2bf(xv.w);
    ((ushort4*)(xbf + b * 1024))[t] = xo;
}

// ---------- MFMA GEMM core: acc = A[128 x K](bf16, row stride 1024) * B(f32->bf16) ----------
// BT=false: B[k][n] row-major (ld=ldb).  BT=true: B[k][n] = Bsrc[n][k]  (C = A * Bsrc^T)
// LDS double-buffered, 1 barrier per 64-wide k-step. Caller does the epilogue.
template <bool BT>
__device__ __forceinline__ void gemm_core(
    const unsigned short* __restrict__ A, const float* __restrict__ Bm,
    const int ldb, const int kchunk, const int k0base, const int n0,
    f32x4 (&acc)[4][2])
{
    __shared__ __align__(16) unsigned short As[2][128 * 72];
    __shared__ __align__(16) unsigned short Bs[2][64 * 72];
    const int t = threadIdx.x;
    const int lane = t & 63, wid = t >> 6;
    const int wm = wid >> 1, wn = wid & 1;
    const int q = lane >> 4, c16 = lane & 15;

    // A staging map: 2 threads per row, 32 bf16 each
    const int arow = t >> 1, ahalf = t & 1;
    const unsigned short* aptr = A + arow * 1024 + k0base + ahalf * 32;
    const int adoff = arow * 72 + ahalf * 32;

    // B staging maps
    const int bnp = t & 31, bkc = t >> 5;   // !BT
    const int bnr = t >> 2, bpart = t & 3;  // BT
    const float* bptr = BT ? (Bm + (size_t)(n0 + bnr) * ldb + k0base + bpart * 16)
                           : (Bm + (size_t)(k0base + bkc * 8) * ldb + n0 + bnp * 2);

    short8v ra0, ra1, ra2, ra3;
    float2 rb0, rb1, rb2, rb3, rb4, rb5, rb6, rb7;  // !BT
    float4 rt0, rt1, rt2, rt3;                      // BT

    auto LOAD = [&](int kk) {
        const int koff = kk << 6;
        const unsigned short* ap = aptr + koff;
        ra0 = *(const short8v*)(ap);      ra1 = *(const short8v*)(ap + 8);
        ra2 = *(const short8v*)(ap + 16); ra3 = *(const short8v*)(ap + 24);
        if (!BT) {
            const float* bp = bptr + (size_t)koff * ldb;
            rb0 = *(const float2*)(bp);                    rb1 = *(const float2*)(bp + (size_t)ldb);
            rb2 = *(const float2*)(bp + (size_t)2 * ldb);  rb3 = *(const float2*)(bp + (size_t)3 * ldb);
            rb4 = *(const float2*)(bp + (size_t)4 * ldb);  rb5 = *(const float2*)(bp + (size_t)5 * ldb);
            rb6 = *(const float2*)(bp + (size_t)6 * ldb);  rb7 = *(const float2*)(bp + (size_t)7 * ldb);
        } else {
            const float* bp = bptr + koff;
            rt0 = *(const float4*)(bp);     rt1 = *(const float4*)(bp + 4);
            rt2 = *(const float4*)(bp + 8); rt3 = *(const float4*)(bp + 12);
        }
    };
    auto STORE_LDS = [&](int buf) {
        unsigned short* ad = &As[buf][adoff];
        *(short8v*)(ad)      = ra0; *(short8v*)(ad + 8)  = ra1;
        *(short8v*)(ad + 16) = ra2; *(short8v*)(ad + 24) = ra3;
        if (!BT) {
            short8v s0, s1;
            s0[0]=(short)f2bf(rb0.x); s1[0]=(short)f2bf(rb0.y);
            s0[1]=(short)f2bf(rb1.x); s1[1]=(short)f2bf(rb1.y);
            s0[2]=(short)f2bf(rb2.x); s1[2]=(short)f2bf(rb2.y);
            s0[3]=(short)f2bf(rb3.x); s1[3]=(short)f2bf(rb3.y);
            s0[4]=(short)f2bf(rb4.x); s1[4]=(short)f2bf(rb4.y);
            s0[5]=(short)f2bf(rb5.x); s1[5]=(short)f2bf(rb5.y);
            s0[6]=(short)f2bf(rb6.x); s1[6]=(short)f2bf(rb6.y);
            s0[7]=(short)f2bf(rb7.x); s1[7]=(short)f2bf(rb7.y);
            *(short8v*)(&Bs[buf][(bnp * 2 + 0) * 72 + bkc * 8]) = s0;
            *(short8v*)(&Bs[buf][(bnp * 2 + 1) * 72 + bkc * 8]) = s1;
        } else {
            short8v s0, s1;
            s0[0]=(short)f2bf(rt0.x); s0[1]=(short)f2bf(rt0.y); s0[2]=(short)f2bf(rt0.z); s0[3]=(short)f2bf(rt0.w);
            s0[4]=(short)f2bf(rt1.x); s0[5]=(short)f2bf(rt1.y); s0[6]=(short)f2bf(rt1.z); s0[7]=(short)f2bf(rt1.w);
            s1[0]=(short)f2bf(rt2.x); s1[1]=(short)f2bf(rt2.y); s1[2]=(short)f2bf(rt2.z); s1[3]=(short)f2bf(rt2.w);
            s1[4]=(short)f2bf(rt3.x); s1[5]=(short)f2bf(rt3.y); s1[6]=(short)f2bf(rt3.z); s1[7]=(short)f2bf(rt3.w);
            *(short8v*)(&Bs[buf][bnr * 72 + bpart * 16])     = s0;
            *(short8v*)(&Bs[buf][bnr * 72 + bpart * 16 + 8]) = s1;
        }
    };

    const int nsteps = kchunk >> 6;
    LOAD(0);
    STORE_LDS(0);
    if (nsteps > 1) LOAD(1);
    __syncthreads();

    for (int kk = 0; kk < nsteps; ++kk) {
        if (kk + 1 < nsteps) STORE_LDS((kk + 1) & 1);
        if (kk + 2 < nsteps) LOAD(kk + 2);
        const unsigned short* Ab = &As[kk & 1][0];
        const unsigned short* Bb = &Bs[kk & 1][0];
        #pragma unroll
        for (int ks = 0; ks < 64; ks += 32) {
            bf16x8 af[4], bfv[2];
            #pragma unroll
            for (int mt = 0; mt < 4; ++mt)
                af[mt] = __builtin_bit_cast(bf16x8,
                    *(const short8v*)(Ab + (wm * 64 + mt * 16 + c16) * 72 + ks + q * 8));
            #pragma unroll
            for (int nt = 0; nt < 2; ++nt)
                bfv[nt] = __builtin_bit_cast(bf16x8,
                    *(const short8v*)(Bb + (wn * 32 + nt * 16 + c16) * 72 + ks + q * 8));
            #pragma unroll
            for (int mt = 0; mt < 4; ++mt)
                #pragma unroll
                for (int nt = 0; nt < 2; ++nt)
                    acc[mt][nt] = __builtin_amdgcn_mfma_f32_16x16x32_bf16(
                        af[mt], bfv[nt], acc[mt][nt], 0, 0, 0);
        }
        if (kk + 1 < nsteps) __syncthreads();
    }
}

// D-frag mapping helper: m = wm*64 + mt*16 + (lane>>4)*4 + j ; n = n0 + wn*32 + nt*16 + (lane&15)

// ---- GEMM1 full-K (16 blocks): hbf = bf16(gelu(cbf @ W1 + b1)) ----
__global__ __launch_bounds__(256, 2) void gemm1h_kernel(
    const unsigned short* __restrict__ cbf, const float* __restrict__ W1,
    const float* __restrict__ b1, unsigned short* __restrict__ hbf)
{
    f32x4 acc[4][2] = {};
    const int n0 = blockIdx.x * 64;
    gemm_core<false>(cbf, W1, 1024, 1024, 0, n0, acc);
    const int t = threadIdx.x, lane = t & 63, wid = t >> 6;
    const int wm = wid >> 1, wn = wid & 1, q = lane >> 4, c16 = lane & 15;
    #pragma unroll
    for (int mt = 0; mt < 4; ++mt) {
        const int m = wm * 64 + mt * 16 + q * 4;
        #pragma unroll
        for (int nt = 0; nt < 2; ++nt) {
            const int n = n0 + wn * 32 + nt * 16 + c16;
            const float bb = b1[n];
            #pragma unroll
            for (int j = 0; j < 4; ++j)
                hbf[(m + j) * 1024 + n] = f2bf(gelu_exact(acc[mt][nt][j] + bb));
        }
    }
}

// ---- mega launch: blocks 0..15 = GEMM3 full-K (P2 = xbf @ base_down),
//                   blocks 16..527 = GEMM2 (w = hbf @ W2 + b2) ----
__global__ __launch_bounds__(256, 2) void gemm23_kernel(
    const unsigned short* __restrict__ hbf, const float* __restrict__ W2,
    const float* __restrict__ b2, float* __restrict__ w,
    const unsigned short* __restrict__ xbf, const float* __restrict__ bdn,
    float* __restrict__ P2)
{
    const bool g3 = blockIdx.x < 16;
    const int n0 = (g3 ? blockIdx.x : (blockIdx.x - 16)) * 64;
    const unsigned short* A = g3 ? xbf : hbf;
    const float* Bm = g3 ? bdn : W2;
    const int ldb = g3 ? 1024 : 32768;
    f32x4 acc[4][2] = {};
    gemm_core<false>(A, Bm, ldb, 1024, 0, n0, acc);
    const int t = threadIdx.x, lane = t & 63, wid = t >> 6;
    const int wm = wid >> 1, wn = wid & 1, q = lane >> 4, c16 = lane & 15;
    #pragma unroll
    for (int mt = 0; mt < 4; ++mt) {
        const int m = wm * 64 + mt * 16 + q * 4;
        #pragma unroll
        for (int nt = 0; nt < 2; ++nt) {
            const int n = n0 + wn * 32 + nt * 16 + c16;
            if (g3) {
                #pragma unroll
                for (int j = 0; j < 4; ++j)
                    P2[(m + j) * 1024 + n] = acc[mt][nt][j];
            } else {
                const float bb = b2[n];
                #pragma unroll
                for (int j = 0; j < 4; ++j)
                    w[(size_t)(m + j) * 32768 + n] = acc[mt][nt][j] + bb;
            }
        }
    }
}

// ---- GEMM4 full-K (16 blocks): out += ybf @ base_up^T ----
__global__ __launch_bounds__(256, 2) void gemm4_kernel(
    const unsigned short* __restrict__ ybf, const float* __restrict__ bup,
    float* __restrict__ out)
{
    f32x4 acc[4][2] = {};
    const int n0 = blockIdx.x * 64;
    gemm_core<true>(ybf, bup, 1024, 1024, 0, n0, acc);
    const int t = threadIdx.x, lane = t & 63, wid = t >> 6;
    const int wm = wid >> 1, wn = wid & 1, q = lane >> 4, c16 = lane & 15;
    #pragma unroll
    for (int mt = 0; mt < 4; ++mt) {
        const int m = wm * 64 + mt * 16 + q * 4;
        #pragma unroll
        for (int nt = 0; nt < 2; ++nt) {
            const int n = n0 + wn * 32 + nt * 16 + c16;
            #pragma unroll
            for (int j = 0; j < 4; ++j)
                out[(m + j) * 1024 + n] += acc[mt][nt][j];
        }
    }
}

// ---------- per-row fused epilogue: t2, y=gelu(.), ybf, t1, out_init ----------
__device__ __forceinline__ void block_reduce8(float a[8], float* out8, float (*scr)[8], int t) {
    #pragma unroll
    for (int r = 0; r < 8; ++r)
        #pragma unroll
        for (int off = 32; off; off >>= 1)
            a[r] += __shfl_xor(a[r], off);
    if ((t & 63) == 0) {
        #pragma unroll
        for (int r = 0; r < 8; ++r) scr[t >> 6][r] = a[r];
    }
    __syncthreads();
    if (t < 8) out8[t] = scr[0][t] + scr[1][t] + scr[2][t] + scr[3][t];
    __syncthreads();
}

__global__ __launch_bounds__(256) void e1big_kernel(
    const float* __restrict__ P2, const float* __restrict__ w,
    const float* __restrict__ x, unsigned short* __restrict__ ybf,
    float* __restrict__ out)
{
    __shared__ float scr[4][8];
    __shared__ float t2s[8], t1s[8];
    const int b = blockIdx.x, t = threadIdx.x;
    const float* wrow = w + (size_t)b * 32768;
    const float* xrow = x + b * 1024;

    // stage 1: t2[r] = sum_d la2[b,d,r] * x[b,d]   (la2 = chunk 2 @ +16384)
    float a[8] = {0,0,0,0,0,0,0,0};
    #pragma unroll
    for (int i = 0; i < 4; ++i) {
        int d = t + i * 256;
        float xv = xrow[d];
        float4 w0 = *(const float4*)(wrow + 16384 + d * 8);
        float4 w1 = *(const float4*)(wrow + 16384 + d * 8 + 4);
        a[0] += xv * w0.x; a[1] += xv * w0.y; a[2] += xv * w0.z; a[3] += xv * w0.w;
        a[4] += xv * w1.x; a[5] += xv * w1.y; a[6] += xv * w1.z; a[7] += xv * w1.w;
    }
    block_reduce8(a, t2s, scr, t);
    float t2v[8];
    #pragma unroll
    for (int r = 0; r < 8; ++r) t2v[r] = t2s[r];

    // stage 2: y = gelu(P2 + lb2 @ t2); accumulate t1 = sum_l lb1[l,:]*y[l]
    float a1[8] = {0,0,0,0,0,0,0,0};
    #pragma unroll
    for (int i = 0; i < 4; ++i) {
        int l = t + i * 256;
        float s = P2[b * 1024 + l];
        float4 w0 = *(const float4*)(wrow + 24576 + l * 8);
        float4 w1 = *(const float4*)(wrow + 24576 + l * 8 + 4);
        s += w0.x*t2v[0] + w0.y*t2v[1] + w0.z*t2v[2] + w0.w*t2v[3]
           + w1.x*t2v[4] + w1.y*t2v[5] + w1.z*t2v[6] + w1.w*t2v[7];
        float y = gelu_exact(s);
        ybf[b * 1024 + l] = f2bf(y);
        float4 l0 = *(const float4*)(wrow + 8192 + l * 8);
        float4 l1 = *(const float4*)(wrow + 8192 + l * 8 + 4);
        a1[0] += y * l0.x; a1[1] += y * l0.y; a1[2] += y * l0.z; a1[3] += y * l0.w;
        a1[4] += y * l1.x; a1[5] += y * l1.y; a1[6] += y * l1.z; a1[7] += y * l1.w;
    }
    block_reduce8(a1, t1s, scr, t);
    float t1v[8];
    #pragma unroll
    for (int r = 0; r < 8; ++r) t1v[r] = t1s[r];

    // stage 3: out_init = x + la1 @ t1   (la1 = chunk 0)
    #pragma unroll
    for (int i = 0; i < 4; ++i) {
        int k = t + i * 256;
        float4 w0 = *(const float4*)(wrow + k * 8);
        float4 w1 = *(const float4*)(wrow + k * 8 + 4);
        out[b * 1024 + k] = xrow[k]
           + w0.x*t1v[0] + w0.y*t1v[1] + w0.z*t1v[2] + w0.w*t1v[3]
           + w1.x*t1v[4] + w1.y*t1v[5] + w1.z*t1v[6] + w1.w*t1v[7];
    }
}

extern "C" void kernel_launch(void* const* d_in, const int* in_sizes, int n_in,
                              void* d_out, int out_size, void* d_ws, size_t ws_size,
                              hipStream_t stream) {
    (void)in_sizes; (void)n_in; (void)out_size; (void)ws_size;
    const float* x        = (const float*)d_in[0];
    const float* ada      = (const float*)d_in[1];
    const float* base_up  = (const float*)d_in[2];
    const float* base_down= (const float*)d_in[3];
    const float* ln_g     = (const float*)d_in[4];
    const float* ln_b     = (const float*)d_in[5];
    const float* W1       = (const float*)d_in[6];
    const float* b1       = (const float*)d_in[7];
    const float* W2       = (const float*)d_in[8];
    const float* b2       = (const float*)d_in[9];

    char* ws = (char*)d_ws;
    float* w            = (float*)(ws + 0);          // 16 MiB
    float* P2           = (float*)(ws + 16777216);   // 512 KiB
    unsigned short* cbf = (unsigned short*)(ws + 17301504); // 256 KiB each
    unsigned short* xbf = (unsigned short*)(ws + 17563648);
    unsigned short* hbf = (unsigned short*)(ws + 17825792);
    unsigned short* ybf = (unsigned short*)(ws + 18087936);

    // 1. LN + bf16 casts
    ln_cast_kernel<<<128, 256, 0, stream>>>(ada, ln_g, ln_b, x, cbf, xbf);
    // 2. GEMM1 full-K + gelu -> hbf
    gemm1h_kernel<<<16, 256, 0, stream>>>(cbf, W1, b1, hbf);
    // 3. GEMM3 (16 blocks) + GEMM2 (512 blocks) in one launch
    gemm23_kernel<<<528, 256, 0, stream>>>(hbf, W2, b2, w, xbf, base_down, P2);
    // 4. fused row epilogue: t2, y, ybf, t1, out = x + la1@t1
    e1big_kernel<<<128, 256, 0, stream>>>(P2, w, x, ybf, (float*)d_out);
    // 5. GEMM4 full-K: out += y @ base_up^T
    gemm4_kernel<<<16, 256, 0, stream>>>(ybf, base_up, (float*)d_out);
}